// Round 7
// baseline (92.223 us; speedup 1.0000x reference)
//
#include <hip/hip_runtime.h>

typedef __attribute__((ext_vector_type(8))) short short8;
typedef __attribute__((ext_vector_type(4))) float f32x4;
typedef unsigned int u32;

#define NB 64
#define NC 3
#define NH 384
#define NW 384
#define HW (NH*NW)
#define NPATCH 576
#define NE 768
#define KDIM 768           // NC*16*16
#define MDIM (NB*NPATCH)   // 36864

#define BM 128
#define BN 256
#define BK 32
#define NBLK_N (NE / BN)       // 3
#define NBLK_M (MDIM / BM)     // 288
#define NWG (NBLK_M * NBLK_N)  // 864
#define NKK (KDIM / BK)        // 24

#define TILE_B_BYTES (BN * BK * 2)                 // 16384
#define WS_B_BYTES (NBLK_N * NKK * TILE_B_BYTES)   // 1,179,648

__device__ __forceinline__ unsigned short f2bf(float f) {
    unsigned int u = __builtin_bit_cast(unsigned int, f);
    u += 0x7fffu + ((u >> 16) & 1u);   // round-to-nearest-even
    return (unsigned short)(u >> 16);
}

// packed f32x2 -> bf16x2 (RNE), 1 VALU inst (no builtin on gfx950)
__device__ __forceinline__ u32 cvtpk(float lo, float hi) {
    u32 r;
    asm("v_cvt_pk_bf16_f32 %0, %1, %2" : "=v"(r) : "v"(lo), "v"(hi));
    return r;
}

// K-step barrier: publish ds_writes only; global loads stay IN FLIGHT.
#define KBAR()  do {                                            \
        asm volatile("s_waitcnt lgkmcnt(0)" ::: "memory");      \
        __builtin_amdgcn_sched_barrier(0);                      \
        __builtin_amdgcn_s_barrier();                           \
        __builtin_amdgcn_sched_barrier(0);                      \
    } while (0)

// ---- pre-pass: proj_w fp32 [E][K] -> bf16 FRAGMENT-ORDER tile images ----
// Tile (bn,kk) = 16KB, 1024 slots of 16B. Slot s: g=s>>6 (fragment 0..15),
// l=s&63 (lane) holds pw[e = bn*256 + g*16 + (l&15)][k = kk*32 + (l>>4)*8 ..+8].
// Wave wc reads fragment ni at byte (wc*4+ni)*1024 + lane*16 (fully coalesced).
__global__ __launch_bounds__(256) void convert_w(
    const float* __restrict__ pw, unsigned char* __restrict__ wsb)
{
    int id = blockIdx.x * 256 + threadIdx.x;   // 72 tiles * 1024 slots = 73728
    int tile = id >> 10;           // bn*NKK + kk
    int s    = id & 1023;
    int bn = tile / NKK;
    int kk = tile - bn * NKK;
    int g = s >> 6, l = s & 63;
    int e = bn * 256 + g * 16 + (l & 15);
    int k = kk * 32 + (l >> 4) * 8;

    const float4 f0 = *reinterpret_cast<const float4*>(pw + (size_t)e * KDIM + k);
    const float4 f1 = *reinterpret_cast<const float4*>(pw + (size_t)e * KDIM + k + 4);
    u32 a = (u32)f2bf(f0.x) | ((u32)f2bf(f0.y) << 16);
    u32 b = (u32)f2bf(f0.z) | ((u32)f2bf(f0.w) << 16);
    u32 c = (u32)f2bf(f1.x) | ((u32)f2bf(f1.y) << 16);
    u32 d = (u32)f2bf(f1.z) | ((u32)f2bf(f1.w) << 16);
    *reinterpret_cast<uint4*>(wsb + (size_t)tile * TILE_B_BYTES + s * 16) =
        make_uint4(a, b, c, d);
}

template <bool WSB>
__global__ __launch_bounds__(512, 4) void patch_embed_gemm(
    const float* __restrict__ x,
    const int* __restrict__ start_h,
    const int* __restrict__ start_w,
    const float* __restrict__ pw,
    const float* __restrict__ pb,
    const unsigned char* __restrict__ wsb,
    float* __restrict__ out)
{
    __shared__ __align__(16) unsigned short lA[2][BM * BK];  // 2 x 8 KB, swizzled
    __shared__ int baseOff[BM];

    const int tid = threadIdx.x;
    // XCD-aware bijective swizzle (864 % 8 == 0): 3 bn-blocks sharing an
    // A-panel run consecutively on one XCD -> gather re-reads hit its L2.
    const int bid  = blockIdx.x;
    const int lbid = (bid & 7) * (NWG / 8) + (bid >> 3);
    const int bm = lbid / NBLK_N;
    const int bn = lbid - bm * NBLK_N;
    const int m0 = bm * BM;
    const int e0 = bn * BN;

    if (tid < BM) {
        int m = m0 + tid;
        int b = m / NPATCH;
        int n = m - b * NPATCH;
        baseOff[tid] = b * (NC * HW) + start_h[b * NPATCH + n] * NW
                     + start_w[b * NPATCH + n];
    }
    __syncthreads();

    const int lane = tid & 63;
    const int wv   = tid >> 6;       // wave 0..7
    const int wr   = wv >> 2;        // 0..1  (64 m-rows)
    const int wc   = wv & 3;         // 0..3  (64 e-cols)
    const int lr   = lane & 15;
    const int lk   = lane >> 4;      // 0..3

    // A staging: 4 threads per row, each 8 contiguous floats (one h-subrow half)
    const int r  = tid >> 2;         // 0..127
    const int j  = tid & 3;          // k-chunk 0..3 (k = j*8..j*8+7)
    const int abase = baseOff[r] + (j >> 1) * NW + (j & 1) * 8;
    const int awr   = r * 64 + ((j ^ (r & 3)) * 16);            // byte, swizzled
    const int ard   = (wr * 64 + lr) * 64 + ((lk ^ (lr & 3)) * 16); // byte
    const int bvoff = wc * 4096 + lane * 16;

    const unsigned char* btiles = wsb + (size_t)bn * NKK * TILE_B_BYTES;
    unsigned char* lab = reinterpret_cast<unsigned char*>(&lA[0][0]);

    f32x4 acc[4][4] = {};
    float4 arA0, arA1, arB0, arB1;
    uint4  br0[4], br1[4];

#define LOADA(KK, R0, R1)                                                     \
    {                                                                         \
        const float* xk = x + abase + ((KK) >> 3) * HW + ((KK) & 7) * 2 * NW; \
        R0 = *reinterpret_cast<const float4*>(xk);                            \
        R1 = *reinterpret_cast<const float4*>(xk + 4);                        \
    }

#define WRITEA(BUF, R0, R1)                                                   \
    *reinterpret_cast<uint4*>(lab + (BUF) * 8192 + awr) = make_uint4(         \
        cvtpk(R0.x, R0.y), cvtpk(R0.z, R0.w),                                 \
        cvtpk(R1.x, R1.y), cvtpk(R1.z, R1.w));

#define LOADB(KK, BR)                                                         \
    if (WSB) {                                                                \
        const unsigned char* bt = btiles + (size_t)(KK) * TILE_B_BYTES + bvoff;\
        _Pragma("unroll")                                                     \
        for (int ni = 0; ni < 4; ++ni)                                        \
            BR[ni] = *reinterpret_cast<const uint4*>(bt + ni * 1024);         \
    } else {                                                                  \
        _Pragma("unroll")                                                     \
        for (int ni = 0; ni < 4; ++ni) {                                      \
            int e = e0 + wc * 64 + ni * 16 + lr;                              \
            const float* bp = pw + (size_t)e * KDIM + (KK) * 32 + lk * 8;     \
            float4 g0 = *reinterpret_cast<const float4*>(bp);                 \
            float4 g1 = *reinterpret_cast<const float4*>(bp + 4);             \
            BR[ni] = make_uint4(cvtpk(g0.x, g0.y), cvtpk(g0.z, g0.w),         \
                                cvtpk(g1.x, g1.y), cvtpk(g1.z, g1.w));        \
        }                                                                     \
    }

#define COMPUTE(BUF, BR)                                                      \
    {                                                                         \
        _Pragma("unroll")                                                     \
        for (int mi = 0; mi < 4; ++mi) {                                      \
            short8 af = *reinterpret_cast<const short8*>(                     \
                lab + (BUF) * 8192 + ard + mi * 1024);                        \
            _Pragma("unroll")                                                 \
            for (int ni = 0; ni < 4; ++ni)                                    \
                acc[mi][ni] = __builtin_amdgcn_mfma_f32_16x16x32_bf16(        \
                    af, __builtin_bit_cast(short8, BR[ni]),                   \
                    acc[mi][ni], 0, 0, 0);                                    \
        }                                                                     \
    }

    // prologue: A(0) staged; A(1) in arA; B(0)/B(1) in flight to br0/br1
    LOADA(0, arA0, arA1)
    LOADB(0, br0)
    LOADB(1, br1)
    WRITEA(0, arA0, arA1)       // compiler inserts counted vmcnt for arA
    LOADA(1, arA0, arA1)
    KBAR();

    #pragma unroll
    for (int kk = 0; kk < NKK; kk += 2) {
        // ---- tile kk: reads lA[0], br0 ----
        if (kk + 2 < NKK) LOADA(kk + 2, arB0, arB1)   // issue early, 1-subiter cover
        if (kk + 1 < NKK) WRITEA(1, arA0, arA1)       // A(kk+1) -> lA[1]
        COMPUTE(0, br0)
        if (kk + 2 < NKK) LOADB(kk + 2, br0)          // br0 now free
        KBAR();
        // ---- tile kk+1: reads lA[1], br1 ----
        if (kk + 3 < NKK) LOADA(kk + 3, arA0, arA1)
        if (kk + 2 < NKK) WRITEA(0, arB0, arB1)       // A(kk+2) -> lA[0]
        COMPUTE(1, br1)
        if (kk + 3 < NKK) LOADB(kk + 3, br1)
        KBAR();
    }

#undef LOADA
#undef WRITEA
#undef LOADB
#undef COMPUTE

    // ---- epilogue: bias + store ----
    float biasv[4];
    #pragma unroll
    for (int ni = 0; ni < 4; ++ni)
        biasv[ni] = pb[e0 + wc * 64 + ni * 16 + lr];

    #pragma unroll
    for (int mi = 0; mi < 4; ++mi) {
        #pragma unroll
        for (int jj = 0; jj < 4; ++jj) {
            int row = m0 + wr * 64 + mi * 16 + lk * 4 + jj;
            float* orow = out + (size_t)row * NE + e0 + wc * 64 + lr;
            #pragma unroll
            for (int ni = 0; ni < 4; ++ni)
                orow[ni * 16] = acc[mi][ni][jj] + biasv[ni];
        }
    }
}

extern "C" void kernel_launch(void* const* d_in, const int* in_sizes, int n_in,
                              void* d_out, int out_size, void* d_ws, size_t ws_size,
                              hipStream_t stream) {
    const float* x  = (const float*)d_in[0];
    const int* sh   = (const int*)d_in[1];
    const int* sw   = (const int*)d_in[2];
    const float* pw = (const float*)d_in[3];
    const float* pb = (const float*)d_in[4];
    float* out = (float*)d_out;

    if (ws_size >= (size_t)WS_B_BYTES) {
        unsigned char* wsb = (unsigned char*)d_ws;
        hipLaunchKernelGGL(convert_w, dim3(288), dim3(256), 0, stream, pw, wsb);
        hipLaunchKernelGGL(patch_embed_gemm<true>, dim3(NWG), dim3(512), 0, stream,
                           x, sh, sw, pw, pb, wsb, out);
    } else {
        hipLaunchKernelGGL(patch_embed_gemm<false>, dim3(NWG), dim3(512), 0, stream,
                           x, sh, sw, pw, pb, (const unsigned char*)nullptr, out);
    }
}